// Round 18
// baseline (887.039 us; speedup 1.0000x reference)
//
#include <hip/hip_runtime.h>
#include <hip/hip_bf16.h>

#define NTOK 1024
#define HDIM 2880
#define IDIM 2880
#define NEXP 8
#define BK 64
#define NT 45  // HDIM/BK

typedef __attribute__((ext_vector_type(4))) float fx4;
typedef __attribute__((ext_vector_type(8))) short sx8;
typedef __attribute__((ext_vector_type(8))) unsigned short usx8;

typedef const __attribute__((address_space(1))) void* gas_p;
typedef __attribute__((address_space(3))) void* las_p;

__device__ __forceinline__ unsigned short f2bf(float f) {
  __hip_bfloat16 b = __float2bfloat16(f);
  return __builtin_bit_cast(unsigned short, b);
}
__device__ __forceinline__ usx8 cvt8(fx4 a, fx4 b) {
  usx8 u = {f2bf(a.x), f2bf(a.y), f2bf(a.z), f2bf(a.w),
            f2bf(b.x), f2bf(b.y), f2bf(b.z), f2bf(b.w)};
  return u;
}
__device__ __forceinline__ float bf2f(unsigned short u) {
  unsigned v = ((unsigned)u) << 16;
  return __builtin_bit_cast(float, v);
}

#define MFMA16(a, b, c) __builtin_amdgcn_mfma_f32_16x16x32_bf16(a, b, c, 0, 0, 0)
#define WAITVM(n)                                        \
  {                                                      \
    asm volatile("s_waitcnt vmcnt(" #n ")" ::: "memory"); \
    __builtin_amdgcn_sched_barrier(0);                   \
  }
#define BAR()                                            \
  {                                                      \
    asm volatile("s_waitcnt lgkmcnt(0)" ::: "memory");   \
    __builtin_amdgcn_s_barrier();                        \
    __builtin_amdgcn_sched_barrier(0);                   \
  }

__global__ __launch_bounds__(256) void rms_router_k(
    const float* __restrict__ x, const float* __restrict__ norm_w,
    const float* __restrict__ gate_w, const float* __restrict__ gate_b,
    unsigned short* __restrict__ t_bf, int* __restrict__ cnt,
    int* __restrict__ tok, int* __restrict__ tokE, int* __restrict__ tokS,
    float* __restrict__ tokW) {
  const int n = blockIdx.x;
  const int tid = threadIdx.x;
  const int wid = tid >> 6, lane = tid & 63;
  const float* xr = x + (size_t)n * HDIM;

  float ss = 0.f;
  for (int h = tid; h < HDIM; h += 256) { float v = xr[h]; ss += v * v; }
  #pragma unroll
  for (int o = 32; o > 0; o >>= 1) ss += __shfl_down(ss, o);
  __shared__ float sred[4];
  if (lane == 0) sred[wid] = ss;
  __syncthreads();
  const float rstd =
      rsqrtf((sred[0] + sred[1] + sred[2] + sred[3]) * (1.0f / HDIM) + 1e-5f);

  float p[NEXP];
  #pragma unroll
  for (int e = 0; e < NEXP; e++) p[e] = 0.f;
  for (int h = tid; h < HDIM; h += 256) {
    float xv = xr[h] * norm_w[h];
    t_bf[(size_t)n * HDIM + h] = f2bf(xv * rstd);
    #pragma unroll
    for (int e = 0; e < NEXP; e++) p[e] += xv * gate_w[e * HDIM + h];
  }
  __shared__ float pls[4][NEXP];
  #pragma unroll
  for (int e = 0; e < NEXP; e++) {
    float v = p[e];
    #pragma unroll
    for (int o = 32; o > 0; o >>= 1) v += __shfl_down(v, o);
    if (lane == 0) pls[wid][e] = v;
  }
  __syncthreads();
  if (tid == 0) {
    float lg[NEXP];
    #pragma unroll
    for (int e = 0; e < NEXP; e++)
      lg[e] = (pls[0][e] + pls[1][e] + pls[2][e] + pls[3][e]) * rstd + gate_b[e];
    unsigned used = 0;
    float val[4];
    int idx[4];
    for (int k = 0; k < 4; k++) {
      float best = -1e30f;
      int bi = 0;
      for (int e = 0; e < NEXP; e++)
        if (!((used >> e) & 1u) && lg[e] > best) { best = lg[e]; bi = e; }
      used |= 1u << bi;
      val[k] = best;
      idx[k] = bi;
    }
    float sum = 0.f, w[4];
    for (int k = 0; k < 4; k++) { w[k] = expf(val[k] - val[0]); sum += w[k]; }
    for (int k = 0; k < 4; k++) {
      int e = idx[k];
      int slot = atomicAdd(&cnt[e], 1);
      tok[e * NTOK + slot] = n;
      tokE[n * 4 + k] = e;
      tokS[n * 4 + k] = slot;
      tokW[n * 4 + k] = w[k] / sum;
    }
  }
}

// Dense-pack gathered token rows; zero-fill to 128-boundary.
__global__ __launch_bounds__(256) void pack_k(
    const unsigned short* __restrict__ t_bf, const int* __restrict__ cnt,
    const int* __restrict__ tok, unsigned short* __restrict__ a_pack) {
  const int e = blockIdx.x >> 8;
  const int r0 = (blockIdx.x & 255) * 4;
  const int ce = cnt[e];
  const int lim = (ce + 127) & ~127;
  if (r0 >= lim) return;
  const int row = r0 + (threadIdx.x >> 6);
  const int lane = threadIdx.x & 63;
  unsigned short* dst = a_pack + ((size_t)e * NTOK + row) * HDIM;
  if (row < ce) {
    const unsigned short* src = t_bf + (size_t)tok[e * NTOK + row] * HDIM;
    for (int c = lane; c < HDIM / 8; c += 64)
      *(usx8*)(dst + c * 8) = *(const usx8*)(src + c * 8);
  } else {
    const usx8 z = {0, 0, 0, 0, 0, 0, 0, 0};
    for (int c = lane; c < HDIM / 8; c += 64) *(usx8*)(dst + c * 8) = z;
  }
}

// GEMM1: 128 slots x 64 I-cols x {G,L}, BK=64, 4 waves (2x2), dbuf 64 KB,
// counted-vmcnt pipeline (T4): raw s_barrier, loads stay in flight across
// barriers. A: depth-1 DMA (L2-resident a_pack). B: depth-2 fp32 reg loads.
// Per-thread vm items/tile: A=4, B=8. Waits: vmcnt(20) pre-compute,
// vmcnt(12) pre-ds_write.
__global__ __launch_bounds__(256) void gemm1_k(
    const unsigned short* __restrict__ a_pack,
    const float* __restrict__ w_gate_up, const float* __restrict__ b_gate_up,
    const int* __restrict__ cnt, unsigned short* __restrict__ act_bf) {
  const int h = blockIdx.x;
  const int u = (h >> 6) * 8 + (h & 7);  // (e, col-slice) < 360
  const int z = (h >> 3) & 7;
  const int e = u / 45;
  const int c0 = (u % 45) * 64;
  const int m0 = z * 128;
  const int ce = cnt[e];
  if (m0 >= ce) return;

  const int tid = threadIdx.x, lane = tid & 63, wid = tid >> 6;
  const int fr = lane & 15, fq = lane >> 4;
  const int wm = wid >> 1, wn = wid & 1;
  const int sw = ((lane & 7) ^ ((lane >> 3) & 7)) * 8;

  __shared__ __align__(16) unsigned short Ash[2][128 * 64];  // 32 KB
  __shared__ __align__(16) unsigned short Bsh[2][128 * 64];  // 32 KB (G:0-63 L:64-127)

  const fx4 FZ = {0.f, 0.f, 0.f, 0.f};
  fx4 accG[4][2], accL[4][2];
  #pragma unroll
  for (int m = 0; m < 4; m++)
    #pragma unroll
    for (int n = 0; n < 2; n++) { accG[m][n] = FZ; accL[m][n] = FZ; }

  const unsigned short* gA[4];
  #pragma unroll
  for (int j = 0; j < 4; ++j) {
    int row = m0 + wid * 32 + j * 8 + (lane >> 3);
    gA[j] = a_pack + ((size_t)e * NTOK + row) * HDIM + sw;
  }
  // B: 128 rows (64 G + 64 L) x 8 chunks = 1024 slots; 4 slots/thread.
  const float* fB[4];
  int bO[4];
  #pragma unroll
  for (int q = 0; q < 4; ++q) {
    int s = tid + 256 * q;
    int bR = s >> 3, bC = s & 7;
    int wr = bR < 64 ? (c0 + bR) : (IDIM + c0 + (bR - 64));
    fB[q] = w_gate_up + ((size_t)e * (2 * IDIM) + wr) * HDIM + bC * 8;
    bO[q] = bR * 64 + ((bC ^ (bR & 7)) * 8);
  }

  fx4 Ra[8], Rb[8];
  #define G1_DMA_A(kt, bb)                                                     \
    {                                                                          \
      const int _ko = (kt)*BK;                                                 \
      _Pragma("unroll") for (int j = 0; j < 4; ++j)                            \
          __builtin_amdgcn_global_load_lds(                                    \
              (gas_p)(gA[j] + _ko), (las_p)&Ash[bb][(wid * 32 + j * 8) * 64],  \
              16, 0, 0);                                                       \
    }
  #define G1_LOADB(R, kt)                                                      \
    {                                                                          \
      const int _ko = (kt)*BK;                                                 \
      _Pragma("unroll") for (int q = 0; q < 4; ++q) {                          \
        R[2 * q] = *(const fx4*)(fB[q] + _ko);                                 \
        R[2 * q + 1] = *(const fx4*)(fB[q] + _ko + 4);                         \
      }                                                                        \
    }
  #define G1_WRITEB(R, bb)                                                     \
    {                                                                          \
      _Pragma("unroll") for (int q = 0; q < 4; ++q)                            \
          *(usx8*)&Bsh[bb][bO[q]] = cvt8(R[2 * q], R[2 * q + 1]);              \
    }
  #define G1_COMPUTE(bb)                                                       \
    {                                                                          \
      _Pragma("unroll") for (int ks = 0; ks < 2; ++ks) {                       \
        const int off = ((ks * 4 + fq) ^ (fr & 7)) * 8;                        \
        sx8 aF[4], bG[2], bL[2];                                               \
        _Pragma("unroll") for (int m = 0; m < 4; ++m) aF[m] =                  \
            *(const sx8*)&Ash[bb][(wm * 64 + m * 16 + fr) * 64 + off];         \
        _Pragma("unroll") for (int n = 0; n < 2; ++n) {                        \
          bG[n] = *(const sx8*)&Bsh[bb][(wn * 32 + n * 16 + fr) * 64 + off];   \
          bL[n] =                                                              \
              *(const sx8*)&Bsh[bb][(64 + wn * 32 + n * 16 + fr) * 64 + off];  \
        }                                                                      \
        __builtin_amdgcn_s_setprio(1);                                         \
        _Pragma("unroll") for (int n = 0; n < 2; ++n)                          \
            _Pragma("unroll") for (int m = 0; m < 4; ++m) {                    \
          accG[m][n] = MFMA16(aF[m], bG[n], accG[m][n]);                       \
          accL[m][n] = MFMA16(aF[m], bL[n], accL[m][n]);                       \
        }                                                                      \
        __builtin_amdgcn_s_setprio(0);                                         \
      }                                                                        \
    }

  // prologue: B(0), A(0), B(1) in flight; wait B(0)+A(0); stage B(0) to LDS.
  G1_LOADB(Ra, 0);
  G1_DMA_A(0, 0);
  G1_LOADB(Rb, 1);
  WAITVM(8);
  G1_WRITEB(Ra, 0);
  BAR();

  // pairs (E=2p, O=2p+1), p=0..21; tile 44 handled after.
  for (int p = 0; p < 22; ++p) {
    const int t0 = 2 * p;
    // EVEN tile t0: LDS buf 0; B(t0+1) in Rb.
    G1_DMA_A(t0 + 1, 1);
    G1_LOADB(Ra, t0 + 2);
    WAITVM(20);  // A(t0) done
    G1_COMPUTE(0);
    WAITVM(12);  // B(t0+1) done
    G1_WRITEB(Rb, 1);
    BAR();
    // ODD tile t0+1: LDS buf 1; B(t0+2) in Ra.
    const int kb = (t0 + 3 < NT) ? (t0 + 3) : (NT - 1);
    G1_DMA_A(t0 + 2, 0);
    G1_LOADB(Rb, kb);
    WAITVM(20);  // A(t0+1) done
    G1_COMPUTE(1);
    WAITVM(12);  // B(t0+2) done
    G1_WRITEB(Ra, 0);
    BAR();
  }
  // tile 44 (even, buf 0): A(44) in flight, B(44) already in LDSB[0].
  WAITVM(8);  // A(44) done
  G1_COMPUTE(0);

  #pragma unroll
  for (int n = 0; n < 2; ++n) {
    const int col = c0 + wn * 32 + n * 16 + fr;
    const float bg = b_gate_up[e * (2 * IDIM) + col];
    const float bl = b_gate_up[e * (2 * IDIM) + IDIM + col];
    #pragma unroll
    for (int m = 0; m < 4; ++m) {
      #pragma unroll
      for (int r = 0; r < 4; ++r) {
        int slot = m0 + wm * 64 + m * 16 + fq * 4 + r;
        if (slot < ce) {
          float gv = accG[m][n][r] + bg;
          float lv = accL[m][n][r] + bl;
          float a = gv * (1.0f / (1.0f + __expf(-1.702f * gv))) * (lv + 1.0f);
          act_bf[((size_t)e * NTOK + slot) * IDIM + col] = f2bf(a);
        }
      }
    }
  }
}

// GEMM2: 128 slots x 96 cols, BK=64, 4 waves (2x2), dbuf 56 KB, same
// counted-vmcnt pipeline. Per-thread vm items/tile: A=4, B=6.
// Waits: vmcnt(16) pre-compute, vmcnt(10) pre-ds_write.
__global__ __launch_bounds__(256) void gemm2_k(
    const unsigned short* __restrict__ act_bf, const float* __restrict__ w_down,
    const float* __restrict__ b_down, const int* __restrict__ cnt,
    unsigned short* __restrict__ outs_bf) {
  const int h = blockIdx.x;
  const int u = (h >> 6) * 8 + (h & 7);  // < 240
  const int z = (h >> 3) & 7;
  const int e = u / 30;
  const int c0 = (u % 30) * 96;
  const int m0 = z * 128;
  const int ce = cnt[e];
  if (m0 >= ce) return;

  const int tid = threadIdx.x, lane = tid & 63, wid = tid >> 6;
  const int fr = lane & 15, fq = lane >> 4;
  const int wm = wid >> 1, wn = wid & 1;
  const int sw = ((lane & 7) ^ ((lane >> 3) & 7)) * 8;

  __shared__ __align__(16) unsigned short Ash[2][128 * 64];  // 32 KB
  __shared__ __align__(16) unsigned short Bsh[2][96 * 64];   // 24 KB

  const fx4 FZ = {0.f, 0.f, 0.f, 0.f};
  fx4 acc[4][3];
  #pragma unroll
  for (int m = 0; m < 4; m++)
    #pragma unroll
    for (int n = 0; n < 3; n++) acc[m][n] = FZ;

  const unsigned short* gA[4];
  #pragma unroll
  for (int j = 0; j < 4; ++j) {
    int row = m0 + wid * 32 + j * 8 + (lane >> 3);
    gA[j] = act_bf + ((size_t)e * NTOK + row) * IDIM + sw;
  }
  const float* fB[3];
  int bO[3];
  #pragma unroll
  for (int q = 0; q < 3; ++q) {
    int s = tid + 256 * q;
    int bR = s >> 3, bC = s & 7;
    fB[q] = w_down + ((size_t)e * HDIM + c0 + bR) * IDIM + bC * 8;
    bO[q] = bR * 64 + ((bC ^ (bR & 7)) * 8);
  }

  fx4 Ra[6], Rb[6];
  #define G2_DMA_A(kt, bb)                                                     \
    {                                                                          \
      const int _ko = (kt)*BK;                                                 \
      _Pragma("unroll") for (int j = 0; j < 4; ++j)                            \
          __builtin_amdgcn_global_load_lds(                                    \
              (gas_p)(gA[j] + _ko), (las_p)&Ash[bb][(wid * 32 + j * 8) * 64],  \
              16, 0, 0);                                                       \
    }
  #define G2_LOADB(R, kt)                                                      \
    {                                                                          \
      const int _ko = (kt)*BK;                                                 \
      _Pragma("unroll") for (int q = 0; q < 3; ++q) {                          \
        R[2 * q] = *(const fx4*)(fB[q] + _ko);                                 \
        R[2 * q + 1] = *(const fx4*)(fB[q] + _ko + 4);                         \
      }                                                                        \
    }
  #define G2_WRITEB(R, bb)                                                     \
    {                                                                          \
      _Pragma("unroll") for (int q = 0; q < 3; ++q)                            \
          *(usx8*)&Bsh[bb][bO[q]] = cvt8(R[2 * q], R[2 * q + 1]);              \
    }
  #define G2_COMPUTE(bb)                                                       \
    {                                                                          \
      _Pragma("unroll") for (int ks = 0; ks < 2; ++ks) {                       \
        const int off = ((ks * 4 + fq) ^ (fr & 7)) * 8;                        \
        sx8 aF[4], bB[3];                                                      \
        _Pragma("unroll") for (int m = 0; m < 4; ++m) aF[m] =                  \
            *(const sx8*)&Ash[bb][(wm * 64 + m * 16 + fr) * 64 + off];         \
        _Pragma("unroll") for (int n = 0; n < 3; ++n) bB[n] =                  \
            *(const sx8*)&Bsh[bb][(wn * 48 + n * 16 + fr) * 64 + off];         \
        __builtin_amdgcn_s_setprio(1);                                         \
        _Pragma("unroll") for (int n = 0; n < 3; ++n)                          \
            _Pragma("unroll") for (int m = 0; m < 4; ++m)                      \
                acc[m][n] = MFMA16(aF[m], bB[n], acc[m][n]);                   \
        __builtin_amdgcn_s_setprio(0);                                         \
      }                                                                        \
    }

  G2_LOADB(Ra, 0);
  G2_DMA_A(0, 0);
  G2_LOADB(Rb, 1);
  WAITVM(6);
  G2_WRITEB(Ra, 0);
  BAR();

  for (int p = 0; p < 22; ++p) {
    const int t0 = 2 * p;
    G2_DMA_A(t0 + 1, 1);
    G2_LOADB(Ra, t0 + 2);
    WAITVM(16);
    G2_COMPUTE(0);
    WAITVM(10);
    G2_WRITEB(Rb, 1);
    BAR();
    const int kb = (t0 + 3 < NT) ? (t0 + 3) : (NT - 1);
    G2_DMA_A(t0 + 2, 0);
    G2_LOADB(Rb, kb);
    WAITVM(16);
    G2_COMPUTE(1);
    WAITVM(10);
    G2_WRITEB(Ra, 0);
    BAR();
  }
  WAITVM(6);
  G2_COMPUTE(0);

  #pragma unroll
  for (int n = 0; n < 3; ++n) {
    const int col = c0 + wn * 48 + n * 16 + fr;
    const float bias = b_down[e * HDIM + col];
    #pragma unroll
    for (int m = 0; m < 4; ++m) {
      #pragma unroll
      for (int r = 0; r < 4; ++r) {
        int slot = m0 + wm * 64 + m * 16 + fq * 4 + r;
        if (slot < ce)
          outs_bf[((size_t)e * NTOK + slot) * HDIM + col] =
              f2bf(acc[m][n][r] + bias);
      }
    }
  }
}

// combine: out[n] = x[n] + sum_k w_k * outs_bf[e_k, s_k]
__global__ __launch_bounds__(256) void combine_k(
    const float* __restrict__ x, const unsigned short* __restrict__ outs_bf,
    const int* __restrict__ tokE, const int* __restrict__ tokS,
    const float* __restrict__ tokW, float* __restrict__ out) {
  const int n = blockIdx.x;
  const unsigned short* src[4];
  float w[4];
  #pragma unroll
  for (int k = 0; k < 4; ++k) {
    int e = tokE[n * 4 + k], s = tokS[n * 4 + k];
    w[k] = tokW[n * 4 + k];
    src[k] = outs_bf + ((size_t)e * NTOK + s) * HDIM;
  }
  const float* xr = x + (size_t)n * HDIM;
  float* orow = out + (size_t)n * HDIM;
  for (int c = threadIdx.x; c < HDIM / 8; c += 256) {
    fx4 lo = *(const fx4*)(xr + c * 8);
    fx4 hi = *(const fx4*)(xr + c * 8 + 4);
    #pragma unroll
    for (int k = 0; k < 4; ++k) {
      usx8 v = *(const usx8*)(src[k] + c * 8);
      lo.x += w[k] * bf2f(v[0]);
      lo.y += w[k] * bf2f(v[1]);
      lo.z += w[k] * bf2f(v[2]);
      lo.w += w[k] * bf2f(v[3]);
      hi.x += w[k] * bf2f(v[4]);
      hi.y += w[k] * bf2f(v[5]);
      hi.z += w[k] * bf2f(v[6]);
      hi.w += w[k] * bf2f(v[7]);
    }
    *(fx4*)(orow + c * 8) = lo;
    *(fx4*)(orow + c * 8 + 4) = hi;
  }
}

extern "C" void kernel_launch(void* const* d_in, const int* in_sizes, int n_in,
                              void* d_out, int out_size, void* d_ws,
                              size_t ws_size, hipStream_t stream) {
  const float* x = (const float*)d_in[0];
  const float* norm_w = (const float*)d_in[1];
  const float* gate_w = (const float*)d_in[2];
  const float* gate_b = (const float*)d_in[3];
  const float* w_gate_up = (const float*)d_in[4];
  const float* b_gate_up = (const float*)d_in[5];
  const float* w_down = (const float*)d_in[6];
  const float* b_down = (const float*)d_in[7];
  float* out = (float*)d_out;

  char* ws = (char*)d_ws;
  size_t off = 0;
  unsigned short* t_bf = (unsigned short*)(ws + off);
  off += (size_t)NTOK * HDIM * 2;
  unsigned short* a_pack = (unsigned short*)(ws + off);
  off += (size_t)NEXP * NTOK * HDIM * 2;
  unsigned short* act_bf = (unsigned short*)(ws + off);
  off += (size_t)NEXP * NTOK * IDIM * 2;
  unsigned short* outs_bf = (unsigned short*)(ws + off);
  off += (size_t)NEXP * NTOK * HDIM * 2;
  int* cnt = (int*)(ws + off);
  off += 256;
  int* tok = (int*)(ws + off);
  off += (size_t)NEXP * NTOK * 4;
  int* tokE = (int*)(ws + off);
  off += (size_t)NTOK * 4 * 4;
  int* tokS = (int*)(ws + off);
  off += (size_t)NTOK * 4 * 4;
  float* tokW = (float*)(ws + off);
  off += (size_t)NTOK * 4 * 4;

  hipMemsetAsync(cnt, 0, NEXP * sizeof(int), stream);
  rms_router_k<<<NTOK, 256, 0, stream>>>(x, norm_w, gate_w, gate_b, t_bf, cnt,
                                         tok, tokE, tokS, tokW);
  pack_k<<<NEXP * 256, 256, 0, stream>>>(t_bf, cnt, tok, a_pack);
  // h = g*64 + z*8 + v : z-twins of one (e,c) share h%8 (same XCD) within a
  // 64-block window -> weight panel HBM-fetched once.
  gemm1_k<<<2880, 256, 0, stream>>>(a_pack, w_gate_up, b_gate_up, cnt, act_bf);
  gemm2_k<<<1920, 256, 0, stream>>>(act_bf, w_down, b_down, cnt, outs_bf);
  combine_k<<<NTOK, 256, 0, stream>>>(x, outs_bf, tokE, tokS, tokW, out);
}